// Round 1
// baseline (289.267 us; speedup 1.0000x reference)
//
#include <hip/hip_runtime.h>

#define N_   64
#define C_   512
#define HW_  1024

// ---------------------------------------------------------------------------
// K1: gap[n*C+c] = mean over the 1024 contiguous spatial elements of x[n,c,:,:]
// One wave per row; 4 rows per 256-thread block. float4 loads (16 B/lane).
// ---------------------------------------------------------------------------
__global__ __launch_bounds__(256) void gap_kernel(const float* __restrict__ x,
                                                  float* __restrict__ gap) {
    int wave = threadIdx.x >> 6;
    int lane = threadIdx.x & 63;
    int row  = blockIdx.x * 4 + wave;                 // row = n*C + c
    const float4* xr = (const float4*)(x + (size_t)row * HW_);
    float s = 0.f;
    #pragma unroll
    for (int j = 0; j < 4; ++j) {
        float4 v = xr[lane + j * 64];
        s += v.x + v.y + v.z + v.w;
    }
    #pragma unroll
    for (int off = 32; off > 0; off >>= 1) s += __shfl_down(s, off, 64);
    if (lane == 0) gap[row] = s * (1.0f / 1024.0f);
}

// ---------------------------------------------------------------------------
// K2: per sample: q,k = relu(conv1d_same(gap, w) + b) (cross-correlation,
// zero-pad), power sums Sq_t = sum_d q^t, Sk_t = sum_c k^t (t=1..6),
// alpha = 1 / (C*C + sum_t Sq_t*Sk_t/t!).  One block per sample.
// ---------------------------------------------------------------------------
__global__ __launch_bounds__(256) void qk_kernel(const float* __restrict__ gap,
    const float* __restrict__ wq, const float* __restrict__ bq,
    const float* __restrict__ wk, const float* __restrict__ bk,
    float* __restrict__ qarr, float* __restrict__ karr,
    float* __restrict__ alph) {
    __shared__ float g[C_ + 2];        // zero-padded gap, g[1+c] = gap[c]
    __shared__ float part[4][12];
    int n = blockIdx.x, tid = threadIdx.x;
    if (tid == 0) { g[0] = 0.f; g[C_ + 1] = 0.f; }
    g[1 + tid]       = gap[n * C_ + tid];
    g[1 + tid + 256] = gap[n * C_ + tid + 256];
    __syncthreads();

    float w0 = wq[0], w1 = wq[1], w2 = wq[2], b0 = bq[0];
    float u0 = wk[0], u1 = wk[1], u2 = wk[2], c0 = bk[0];

    float sq[6] = {0, 0, 0, 0, 0, 0};
    float sk[6] = {0, 0, 0, 0, 0, 0};
    #pragma unroll
    for (int j = 0; j < 2; ++j) {
        int c = tid + j * 256;
        // cross-correlation: out[c] = w0*in[c-1] + w1*in[c] + w2*in[c+1]
        float qv = fmaxf(0.f, w0 * g[c] + w1 * g[c + 1] + w2 * g[c + 2] + b0);
        float kv = fmaxf(0.f, u0 * g[c] + u1 * g[c + 1] + u2 * g[c + 2] + c0);
        qarr[n * C_ + c] = qv;
        karr[n * C_ + c] = kv;
        float pq = qv, pk = kv;
        #pragma unroll
        for (int t = 0; t < 6; ++t) { sq[t] += pq; pq *= qv; sk[t] += pk; pk *= kv; }
    }

    // block-reduce 12 scalars: wave shuffle -> LDS partials -> thread 0
    int lane = tid & 63, wv = tid >> 6;
    float vals[12];
    #pragma unroll
    for (int t = 0; t < 6; ++t) { vals[t] = sq[t]; vals[6 + t] = sk[t]; }
    #pragma unroll
    for (int j = 0; j < 12; ++j) {
        float v = vals[j];
        #pragma unroll
        for (int off = 32; off > 0; off >>= 1) v += __shfl_down(v, off, 64);
        if (lane == 0) part[wv][j] = v;
    }
    __syncthreads();
    if (tid == 0) {
        const float inv_fact[6] = {1.f, 0.5f, 1.f / 6.f, 1.f / 24.f,
                                   1.f / 120.f, 1.f / 720.f};
        float S = (float)C_ * (float)C_;   // t=0 term: 512*512 ones
        #pragma unroll
        for (int t = 0; t < 6; ++t) {
            float tq = 0.f, tk = 0.f;
            for (int w = 0; w < 4; ++w) { tq += part[w][t]; tk += part[w][6 + t]; }
            S += tq * tk * inv_fact[t];
        }
        alph[n] = 1.0f / S;
    }
}

// ---------------------------------------------------------------------------
// K3: per (sample, 256-column spatial tile). Thread <-> spatial column s.
// Pass A: stream x down c, accumulate 7 moments m_t[s] = sum_c k_c^t x[c,s]
//         in registers. Pass B: out[d,s] = x[d,s] * Horner_q_d(m), no barrier
//         between passes (moments are thread-private).
// ---------------------------------------------------------------------------
__global__ __launch_bounds__(256) void att_kernel(const float* __restrict__ x,
    const float* __restrict__ qarr, const float* __restrict__ karr,
    const float* __restrict__ alph, float* __restrict__ out) {
    __shared__ float ksh[C_];
    __shared__ float qsh[C_];
    int bx = blockIdx.x;
    int n = bx >> 2, tile = bx & 3, tid = threadIdx.x;
    int s = tile * 256 + tid;
    ksh[tid]       = karr[n * C_ + tid];
    ksh[tid + 256] = karr[n * C_ + tid + 256];
    qsh[tid]       = qarr[n * C_ + tid];
    qsh[tid + 256] = qarr[n * C_ + tid + 256];
    float alpha = alph[n];
    __syncthreads();

    const float* xb = x + (size_t)n * C_ * HW_ + s;
    float m0 = 0, m1 = 0, m2 = 0, m3 = 0, m4 = 0, m5 = 0, m6 = 0;
    #pragma unroll 8
    for (int c = 0; c < C_; ++c) {
        float xv = xb[c * HW_];          // coalesced: lanes = consecutive s
        float kc = ksh[c];               // LDS broadcast
        float p = xv;
        m0 += p; p *= kc;
        m1 += p; p *= kc;
        m2 += p; p *= kc;
        m3 += p; p *= kc;
        m4 += p; p *= kc;
        m5 += p; p *= kc;
        m6 += p;
    }
    m0 *= alpha;
    m1 *= alpha;
    m2 *= alpha * 0.5f;
    m3 *= alpha * (1.f / 6.f);
    m4 *= alpha * (1.f / 24.f);
    m5 *= alpha * (1.f / 120.f);
    m6 *= alpha * (1.f / 720.f);

    float* ob = out + (size_t)n * C_ * HW_ + s;
    #pragma unroll 8
    for (int d = 0; d < C_; ++d) {
        float q = qsh[d];
        float att = fmaf(q, m6, m5);
        att = fmaf(q, att, m4);
        att = fmaf(q, att, m3);
        att = fmaf(q, att, m2);
        att = fmaf(q, att, m1);
        att = fmaf(q, att, m0);
        ob[d * HW_] = xb[d * HW_] * att; // second x read: L3-resident
    }
}

// ---------------------------------------------------------------------------
extern "C" void kernel_launch(void* const* d_in, const int* in_sizes, int n_in,
                              void* d_out, int out_size, void* d_ws, size_t ws_size,
                              hipStream_t stream) {
    const float* x  = (const float*)d_in[0];
    const float* wq = (const float*)d_in[1];
    const float* bq = (const float*)d_in[2];
    const float* wk = (const float*)d_in[3];
    const float* bk = (const float*)d_in[4];
    float* out = (float*)d_out;

    float* ws   = (float*)d_ws;
    float* gap  = ws;                      // N*C        = 32768
    float* qarr = ws + 32768;              // N*C
    float* karr = ws + 65536;              // N*C
    float* alph = ws + 98304;              // N

    gap_kernel<<<dim3(N_ * C_ / 4), dim3(256), 0, stream>>>(x, gap);
    qk_kernel<<<dim3(N_), dim3(256), 0, stream>>>(gap, wq, bq, wk, bk,
                                                  qarr, karr, alph);
    att_kernel<<<dim3(N_ * 4), dim3(256), 0, stream>>>(x, qarr, karr, alph, out);
}

// Round 2
// 286.114 us; speedup vs baseline: 1.0110x; 1.0110x over previous
//
#include <hip/hip_runtime.h>

#define N_   64
#define C_   512
#define HW_  1024
#define CH_  8     // c-chunks for moments partials
#define DC_  8     // d-chunks for apply

// float4 helpers (component-wise)
__device__ __forceinline__ float4 f4_add(const float4 a, const float4 b) {
    return make_float4(a.x + b.x, a.y + b.y, a.z + b.z, a.w + b.w);
}
__device__ __forceinline__ float4 f4_muls(const float4 a, const float s) {
    return make_float4(a.x * s, a.y * s, a.z * s, a.w * s);
}
__device__ __forceinline__ float4 f4_fma_s(const float s, const float4 a, const float4 b) {
    // s*a + b
    return make_float4(fmaf(s, a.x, b.x), fmaf(s, a.y, b.y),
                       fmaf(s, a.z, b.z), fmaf(s, a.w, b.w));
}
__device__ __forceinline__ float4 f4_mul(const float4 a, const float4 b) {
    return make_float4(a.x * b.x, a.y * b.y, a.z * b.z, a.w * b.w);
}

// ---------------------------------------------------------------------------
// K1: gap[n*C+c] = mean over 1024 contiguous spatial elements.
// One wave per row, 4 rows per block, float4 loads.
// ---------------------------------------------------------------------------
__global__ __launch_bounds__(256) void gap_kernel(const float* __restrict__ x,
                                                  float* __restrict__ gap) {
    int wave = threadIdx.x >> 6;
    int lane = threadIdx.x & 63;
    int row  = blockIdx.x * 4 + wave;                 // row = n*C + c
    const float4* xr = (const float4*)(x + (size_t)row * HW_);
    float s = 0.f;
    #pragma unroll
    for (int j = 0; j < 4; ++j) {
        float4 v = xr[lane + j * 64];
        s += v.x + v.y + v.z + v.w;
    }
    #pragma unroll
    for (int off = 32; off > 0; off >>= 1) s += __shfl_down(s, off, 64);
    if (lane == 0) gap[row] = s * (1.0f / 1024.0f);
}

// ---------------------------------------------------------------------------
// K2: per sample: q,k = relu(conv1d_same(gap)) ; power sums ; alpha = 1/S.
// ---------------------------------------------------------------------------
__global__ __launch_bounds__(256) void qk_kernel(const float* __restrict__ gap,
    const float* __restrict__ wq, const float* __restrict__ bq,
    const float* __restrict__ wk, const float* __restrict__ bk,
    float* __restrict__ qarr, float* __restrict__ karr,
    float* __restrict__ alph) {
    __shared__ float g[C_ + 2];
    __shared__ float part[4][12];
    int n = blockIdx.x, tid = threadIdx.x;
    if (tid == 0) { g[0] = 0.f; g[C_ + 1] = 0.f; }
    g[1 + tid]       = gap[n * C_ + tid];
    g[1 + tid + 256] = gap[n * C_ + tid + 256];
    __syncthreads();

    float w0 = wq[0], w1 = wq[1], w2 = wq[2], b0 = bq[0];
    float u0 = wk[0], u1 = wk[1], u2 = wk[2], c0 = bk[0];

    float sq[6] = {0, 0, 0, 0, 0, 0};
    float sk[6] = {0, 0, 0, 0, 0, 0};
    #pragma unroll
    for (int j = 0; j < 2; ++j) {
        int c = tid + j * 256;
        float qv = fmaxf(0.f, w0 * g[c] + w1 * g[c + 1] + w2 * g[c + 2] + b0);
        float kv = fmaxf(0.f, u0 * g[c] + u1 * g[c + 1] + u2 * g[c + 2] + c0);
        qarr[n * C_ + c] = qv;
        karr[n * C_ + c] = kv;
        float pq = qv, pk = kv;
        #pragma unroll
        for (int t = 0; t < 6; ++t) { sq[t] += pq; pq *= qv; sk[t] += pk; pk *= kv; }
    }

    int lane = tid & 63, wv = tid >> 6;
    float vals[12];
    #pragma unroll
    for (int t = 0; t < 6; ++t) { vals[t] = sq[t]; vals[6 + t] = sk[t]; }
    #pragma unroll
    for (int j = 0; j < 12; ++j) {
        float v = vals[j];
        #pragma unroll
        for (int off = 32; off > 0; off >>= 1) v += __shfl_down(v, off, 64);
        if (lane == 0) part[wv][j] = v;
    }
    __syncthreads();
    if (tid == 0) {
        const float inv_fact[6] = {1.f, 0.5f, 1.f / 6.f, 1.f / 24.f,
                                   1.f / 120.f, 1.f / 720.f};
        float S = (float)C_ * (float)C_;
        #pragma unroll
        for (int t = 0; t < 6; ++t) {
            float tq = 0.f, tk = 0.f;
            for (int w = 0; w < 4; ++w) { tq += part[w][t]; tk += part[w][6 + t]; }
            S += tq * tk * inv_fact[t];
        }
        alph[n] = 1.0f / S;
    }
}

// ---------------------------------------------------------------------------
// K3: partial moments. Block = (n, c-chunk of 64). Thread owns 4 consecutive
// s (float4). part[chunk][n][t][s] += sum_{c in chunk} k_c^t * x[n,c,s].
// ---------------------------------------------------------------------------
__global__ __launch_bounds__(256) void moments_kernel(const float* __restrict__ x,
    const float* __restrict__ karr, float* __restrict__ part) {
    int b = blockIdx.x;
    int n = b >> 3, chunk = b & 7;
    int tid = threadIdx.x;
    __shared__ float ksh[64];
    if (tid < 64) ksh[tid] = karr[n * C_ + chunk * 64 + tid];
    __syncthreads();

    const float4* xb = (const float4*)(x + (size_t)(n * C_ + chunk * 64) * HW_) + tid;
    float4 m0 = make_float4(0, 0, 0, 0), m1 = m0, m2 = m0, m3 = m0,
           m4 = m0, m5 = m0, m6 = m0;
    #pragma unroll 8
    for (int c = 0; c < 64; ++c) {
        float4 xv = xb[c * 256];         // 64 lanes * 16B = 1 KiB / instr
        float kc = ksh[c];
        float4 p = xv;
        m0 = f4_add(m0, p); p = f4_muls(p, kc);
        m1 = f4_add(m1, p); p = f4_muls(p, kc);
        m2 = f4_add(m2, p); p = f4_muls(p, kc);
        m3 = f4_add(m3, p); p = f4_muls(p, kc);
        m4 = f4_add(m4, p); p = f4_muls(p, kc);
        m5 = f4_add(m5, p); p = f4_muls(p, kc);
        m6 = f4_add(m6, p);
    }
    // part laid out as float4: [((chunk*N + n)*7 + t)*256 + tid]
    float4* pp = (float4*)part + (size_t)((chunk * N_ + n) * 7) * 256 + tid;
    pp[0 * 256] = m0; pp[1 * 256] = m1; pp[2 * 256] = m2; pp[3 * 256] = m3;
    pp[4 * 256] = m4; pp[5 * 256] = m5; pp[6 * 256] = m6;
}

// ---------------------------------------------------------------------------
// K4: reduce partials over chunks, fold alpha/t!. Block = (n, t) pair
// (block-uniform scale -> scalar). Thread owns one float4 (4 s).
// ---------------------------------------------------------------------------
__global__ __launch_bounds__(256) void reduce_kernel(const float* __restrict__ part,
    const float* __restrict__ alph, float* __restrict__ mom) {
    int b = blockIdx.x;
    int n = b / 7, t = b % 7;
    int tid = threadIdx.x;
    const float inv_fact[7] = {1.f, 1.f, 0.5f, 1.f / 6.f, 1.f / 24.f,
                               1.f / 120.f, 1.f / 720.f};
    float scale = alph[n] * inv_fact[t];
    const float4* pp = (const float4*)part;
    float4 acc = make_float4(0, 0, 0, 0);
    #pragma unroll
    for (int chunk = 0; chunk < CH_; ++chunk)
        acc = f4_add(acc, pp[(size_t)((chunk * N_ + n) * 7 + t) * 256 + tid]);
    ((float4*)mom)[(size_t)(n * 7 + t) * 256 + tid] = f4_muls(acc, scale);
}

// ---------------------------------------------------------------------------
// K5: apply. Block = (n, d-chunk of 64). Thread owns 4 consecutive s.
// out[n,d,s] = x[n,d,s] * Horner_{q_d}(mom[n,:,s]).
// ---------------------------------------------------------------------------
__global__ __launch_bounds__(256) void apply_kernel(const float* __restrict__ x,
    const float* __restrict__ qarr, const float* __restrict__ mom,
    float* __restrict__ out) {
    int b = blockIdx.x;
    int n = b >> 3, dchunk = b & 7;
    int tid = threadIdx.x;
    __shared__ float qsh[64];
    if (tid < 64) qsh[tid] = qarr[n * C_ + dchunk * 64 + tid];
    __syncthreads();

    const float4* mp = (const float4*)mom + (size_t)(n * 7) * 256 + tid;
    float4 m0 = mp[0 * 256], m1 = mp[1 * 256], m2 = mp[2 * 256],
           m3 = mp[3 * 256], m4 = mp[4 * 256], m5 = mp[5 * 256],
           m6 = mp[6 * 256];

    const float4* xb = (const float4*)(x + (size_t)(n * C_ + dchunk * 64) * HW_) + tid;
    float4*       ob = (float4*)(out + (size_t)(n * C_ + dchunk * 64) * HW_) + tid;
    #pragma unroll 8
    for (int d = 0; d < 64; ++d) {
        float q = qsh[d];
        float4 att = f4_fma_s(q, m6, m5);
        att = f4_fma_s(q, att, m4);
        att = f4_fma_s(q, att, m3);
        att = f4_fma_s(q, att, m2);
        att = f4_fma_s(q, att, m1);
        att = f4_fma_s(q, att, m0);
        float4 xv = xb[d * 256];
        ob[d * 256] = f4_mul(xv, att);
    }
}

// ---------------------------------------------------------------------------
extern "C" void kernel_launch(void* const* d_in, const int* in_sizes, int n_in,
                              void* d_out, int out_size, void* d_ws, size_t ws_size,
                              hipStream_t stream) {
    const float* x  = (const float*)d_in[0];
    const float* wq = (const float*)d_in[1];
    const float* bq = (const float*)d_in[2];
    const float* wk = (const float*)d_in[3];
    const float* bk = (const float*)d_in[4];
    float* out = (float*)d_out;

    float* ws   = (float*)d_ws;
    float* gap  = ws;                      // N*C   = 32768 floats
    float* qarr = ws + 32768;              // N*C
    float* karr = ws + 65536;              // N*C
    float* alph = ws + 98304;              // N (pad to 64)
    float* part = ws + 98368;              // CH*N*7*1024 = 3,670,016 floats
    float* mom  = part + (size_t)CH_ * N_ * 7 * 1024;  // N*7*1024 = 458,752

    gap_kernel    <<<dim3(N_ * C_ / 4), dim3(256), 0, stream>>>(x, gap);
    qk_kernel     <<<dim3(N_),          dim3(256), 0, stream>>>(gap, wq, bq, wk, bk,
                                                                qarr, karr, alph);
    moments_kernel<<<dim3(N_ * CH_),    dim3(256), 0, stream>>>(x, karr, part);
    reduce_kernel <<<dim3(N_ * 7),      dim3(256), 0, stream>>>(part, alph, mom);
    apply_kernel  <<<dim3(N_ * DC_),    dim3(256), 0, stream>>>(x, qarr, mom, out);
}

// Round 3
// 283.241 us; speedup vs baseline: 1.0213x; 1.0101x over previous
//
#include <hip/hip_runtime.h>

#define N_   64
#define C_   512
#define HW_  1024
#define CH_  8     // c-chunks for moments partials
#define DC_  8     // d-chunks for apply

typedef float f4v __attribute__((ext_vector_type(4)));

// float4 helpers (component-wise)
__device__ __forceinline__ float4 f4_add(const float4 a, const float4 b) {
    return make_float4(a.x + b.x, a.y + b.y, a.z + b.z, a.w + b.w);
}
__device__ __forceinline__ float4 f4_muls(const float4 a, const float s) {
    return make_float4(a.x * s, a.y * s, a.z * s, a.w * s);
}
__device__ __forceinline__ float4 f4_fma_s(const float s, const float4 a, const float4 b) {
    return make_float4(fmaf(s, a.x, b.x), fmaf(s, a.y, b.y),
                       fmaf(s, a.z, b.z), fmaf(s, a.w, b.w));
}

// ---------------------------------------------------------------------------
// K1: gap[n*C+c] = mean over 1024 contiguous spatial elements.
// One wave per row, 4 rows per block, float4 loads. Normal (caching) loads:
// this pass intentionally warms L3 with x for the later passes.
// ---------------------------------------------------------------------------
__global__ __launch_bounds__(256) void gap_kernel(const float* __restrict__ x,
                                                  float* __restrict__ gap) {
    int wave = threadIdx.x >> 6;
    int lane = threadIdx.x & 63;
    int row  = blockIdx.x * 4 + wave;                 // row = n*C + c
    const float4* xr = (const float4*)(x + (size_t)row * HW_);
    float s = 0.f;
    #pragma unroll
    for (int j = 0; j < 4; ++j) {
        float4 v = xr[lane + j * 64];
        s += v.x + v.y + v.z + v.w;
    }
    #pragma unroll
    for (int off = 32; off > 0; off >>= 1) s += __shfl_down(s, off, 64);
    if (lane == 0) gap[row] = s * (1.0f / 1024.0f);
}

// ---------------------------------------------------------------------------
// K2: per sample: q,k = relu(conv1d_same(gap)) ; power sums ; alpha = 1/S.
// ---------------------------------------------------------------------------
__global__ __launch_bounds__(256) void qk_kernel(const float* __restrict__ gap,
    const float* __restrict__ wq, const float* __restrict__ bq,
    const float* __restrict__ wk, const float* __restrict__ bk,
    float* __restrict__ qarr, float* __restrict__ karr,
    float* __restrict__ alph) {
    __shared__ float g[C_ + 2];
    __shared__ float part[4][12];
    int n = blockIdx.x, tid = threadIdx.x;
    if (tid == 0) { g[0] = 0.f; g[C_ + 1] = 0.f; }
    g[1 + tid]       = gap[n * C_ + tid];
    g[1 + tid + 256] = gap[n * C_ + tid + 256];
    __syncthreads();

    float w0 = wq[0], w1 = wq[1], w2 = wq[2], b0 = bq[0];
    float u0 = wk[0], u1 = wk[1], u2 = wk[2], c0 = bk[0];

    float sq[6] = {0, 0, 0, 0, 0, 0};
    float sk[6] = {0, 0, 0, 0, 0, 0};
    #pragma unroll
    for (int j = 0; j < 2; ++j) {
        int c = tid + j * 256;
        float qv = fmaxf(0.f, w0 * g[c] + w1 * g[c + 1] + w2 * g[c + 2] + b0);
        float kv = fmaxf(0.f, u0 * g[c] + u1 * g[c + 1] + u2 * g[c + 2] + c0);
        qarr[n * C_ + c] = qv;
        karr[n * C_ + c] = kv;
        float pq = qv, pk = kv;
        #pragma unroll
        for (int t = 0; t < 6; ++t) { sq[t] += pq; pq *= qv; sk[t] += pk; pk *= kv; }
    }

    int lane = tid & 63, wv = tid >> 6;
    float vals[12];
    #pragma unroll
    for (int t = 0; t < 6; ++t) { vals[t] = sq[t]; vals[6 + t] = sk[t]; }
    #pragma unroll
    for (int j = 0; j < 12; ++j) {
        float v = vals[j];
        #pragma unroll
        for (int off = 32; off > 0; off >>= 1) v += __shfl_down(v, off, 64);
        if (lane == 0) part[wv][j] = v;
    }
    __syncthreads();
    if (tid == 0) {
        const float inv_fact[6] = {1.f, 0.5f, 1.f / 6.f, 1.f / 24.f,
                                   1.f / 120.f, 1.f / 720.f};
        float S = (float)C_ * (float)C_;
        #pragma unroll
        for (int t = 0; t < 6; ++t) {
            float tq = 0.f, tk = 0.f;
            for (int w = 0; w < 4; ++w) { tq += part[w][t]; tk += part[w][6 + t]; }
            S += tq * tk * inv_fact[t];
        }
        alph[n] = 1.0f / S;
    }
}

// ---------------------------------------------------------------------------
// K3: partial moments. Block = (n, c-chunk of 64). Thread owns 4 consecutive
// s (float4). Normal x loads (keep L3-resident for apply).
// ---------------------------------------------------------------------------
__global__ __launch_bounds__(256) void moments_kernel(const float* __restrict__ x,
    const float* __restrict__ karr, float* __restrict__ part) {
    int b = blockIdx.x;
    int n = b >> 3, chunk = b & 7;
    int tid = threadIdx.x;
    __shared__ float ksh[64];
    if (tid < 64) ksh[tid] = karr[n * C_ + chunk * 64 + tid];
    __syncthreads();

    const float4* xb = (const float4*)(x + (size_t)(n * C_ + chunk * 64) * HW_) + tid;
    float4 m0 = make_float4(0, 0, 0, 0), m1 = m0, m2 = m0, m3 = m0,
           m4 = m0, m5 = m0, m6 = m0;
    #pragma unroll 8
    for (int c = 0; c < 64; ++c) {
        float4 xv = xb[c * 256];
        float kc = ksh[c];
        float4 p = xv;
        m0 = f4_add(m0, p); p = f4_muls(p, kc);
        m1 = f4_add(m1, p); p = f4_muls(p, kc);
        m2 = f4_add(m2, p); p = f4_muls(p, kc);
        m3 = f4_add(m3, p); p = f4_muls(p, kc);
        m4 = f4_add(m4, p); p = f4_muls(p, kc);
        m5 = f4_add(m5, p); p = f4_muls(p, kc);
        m6 = f4_add(m6, p);
    }
    float4* pp = (float4*)part + (size_t)((chunk * N_ + n) * 7) * 256 + tid;
    pp[0 * 256] = m0; pp[1 * 256] = m1; pp[2 * 256] = m2; pp[3 * 256] = m3;
    pp[4 * 256] = m4; pp[5 * 256] = m5; pp[6 * 256] = m6;
}

// ---------------------------------------------------------------------------
// K4: reduce partials over chunks, fold alpha/t!. Block = (n, t).
// ---------------------------------------------------------------------------
__global__ __launch_bounds__(256) void reduce_kernel(const float* __restrict__ part,
    const float* __restrict__ alph, float* __restrict__ mom) {
    int b = blockIdx.x;
    int n = b / 7, t = b % 7;
    int tid = threadIdx.x;
    const float inv_fact[7] = {1.f, 1.f, 0.5f, 1.f / 6.f, 1.f / 24.f,
                               1.f / 120.f, 1.f / 720.f};
    float scale = alph[n] * inv_fact[t];
    const float4* pp = (const float4*)part;
    float4 acc = make_float4(0, 0, 0, 0);
    #pragma unroll
    for (int chunk = 0; chunk < CH_; ++chunk)
        acc = f4_add(acc, pp[(size_t)((chunk * N_ + n) * 7 + t) * 256 + tid]);
    ((float4*)mom)[(size_t)(n * 7 + t) * 256 + tid] = f4_muls(acc, scale);
}

// ---------------------------------------------------------------------------
// K5: apply. Block = (n, d-chunk of 64). Thread owns 4 consecutive s.
// x loads are NON-TEMPORAL (last use — hit L3 but don't re-allocate);
// out stores are NON-TEMPORAL (never re-read — don't evict x from L2/L3).
// ---------------------------------------------------------------------------
__global__ __launch_bounds__(256) void apply_kernel(const float* __restrict__ x,
    const float* __restrict__ qarr, const float* __restrict__ mom,
    float* __restrict__ out) {
    int b = blockIdx.x;
    int n = b >> 3, dchunk = b & 7;
    int tid = threadIdx.x;
    __shared__ float qsh[64];
    if (tid < 64) qsh[tid] = qarr[n * C_ + dchunk * 64 + tid];
    __syncthreads();

    const float4* mp = (const float4*)mom + (size_t)(n * 7) * 256 + tid;
    float4 m0 = mp[0 * 256], m1 = mp[1 * 256], m2 = mp[2 * 256],
           m3 = mp[3 * 256], m4 = mp[4 * 256], m5 = mp[5 * 256],
           m6 = mp[6 * 256];

    const f4v* xb = (const f4v*)(x + (size_t)(n * C_ + dchunk * 64) * HW_) + tid;
    f4v*       ob = (f4v*)(out + (size_t)(n * C_ + dchunk * 64) * HW_) + tid;
    #pragma unroll 8
    for (int d = 0; d < 64; ++d) {
        float q = qsh[d];
        float4 att = f4_fma_s(q, m6, m5);
        att = f4_fma_s(q, att, m4);
        att = f4_fma_s(q, att, m3);
        att = f4_fma_s(q, att, m2);
        att = f4_fma_s(q, att, m1);
        att = f4_fma_s(q, att, m0);
        f4v xv = __builtin_nontemporal_load(xb + d * 256);
        f4v res;
        res.x = xv.x * att.x; res.y = xv.y * att.y;
        res.z = xv.z * att.z; res.w = xv.w * att.w;
        __builtin_nontemporal_store(res, ob + d * 256);
    }
}

// ---------------------------------------------------------------------------
extern "C" void kernel_launch(void* const* d_in, const int* in_sizes, int n_in,
                              void* d_out, int out_size, void* d_ws, size_t ws_size,
                              hipStream_t stream) {
    const float* x  = (const float*)d_in[0];
    const float* wq = (const float*)d_in[1];
    const float* bq = (const float*)d_in[2];
    const float* wk = (const float*)d_in[3];
    const float* bk = (const float*)d_in[4];
    float* out = (float*)d_out;

    float* ws   = (float*)d_ws;
    float* gap  = ws;                      // N*C   = 32768 floats
    float* qarr = ws + 32768;              // N*C
    float* karr = ws + 65536;              // N*C
    float* alph = ws + 98304;              // N (pad to 64)
    float* part = ws + 98368;              // CH*N*7*1024 = 3,670,016 floats
    float* mom  = part + (size_t)CH_ * N_ * 7 * 1024;  // N*7*1024 = 458,752

    gap_kernel    <<<dim3(N_ * C_ / 4), dim3(256), 0, stream>>>(x, gap);
    qk_kernel     <<<dim3(N_),          dim3(256), 0, stream>>>(gap, wq, bq, wk, bk,
                                                                qarr, karr, alph);
    moments_kernel<<<dim3(N_ * CH_),    dim3(256), 0, stream>>>(x, karr, part);
    reduce_kernel <<<dim3(N_ * 7),      dim3(256), 0, stream>>>(part, alph, mom);
    apply_kernel  <<<dim3(N_ * DC_),    dim3(256), 0, stream>>>(x, qarr, mom, out);
}